// Round 9
// baseline (283.798 us; speedup 1.0000x reference)
//
#include <hip/hip_runtime.h>
#include <hip/hip_bf16.h>

// Fused span-pair + attention-pooling model for MI355X (gfx950).
// B=8, N=128, H=768, C=5, P = N(N+1)/2 = 8256.

#define B_ 8
#define N_ 128
#define H_ 768
#define C_ 5
#define P_ 8256
#define TP 96        // pairs per block (8256 = 86*96 exactly)
#define NBLK 86
#define NSTEP 24     // K steps of 32
#define BSLAB 49152  // one W4 k-step slice: 4 koct * 768 cols * 16 B

typedef short bf16x8 __attribute__((ext_vector_type(8)));
typedef float f32x4 __attribute__((ext_vector_type(4)));

__device__ __forceinline__ float bf2f(unsigned short u){
  union { unsigned u; float f; } v; v.u = ((unsigned)u) << 16; return v.f;
}
__device__ __forceinline__ unsigned short f2bf(float f){
  union { float f; unsigned u; } v; v.f = f;
  unsigned r = v.u + 0x7FFFu + ((v.u >> 16) & 1u);
  return (unsigned short)(r >> 16);
}
__device__ __forceinline__ float tanh_fast(float x){
  float e = __expf(2.f * x);
  return 1.f - 2.f / (e + 1.f);
}
// bf16 product pack via v_cvt_pk_bf16_f32 (RNE, 1 instr per 2 elems)
__device__ __forceinline__ bf16x8 prodpack(bf16x8 x, bf16x8 y){
  union { bf16x8 v; unsigned u[4]; } o;
  #pragma unroll
  for (int e2 = 0; e2 < 4; e2++){
    float p0 = bf2f((unsigned short)x[e2*2])   * bf2f((unsigned short)y[e2*2]);
    float p1 = bf2f((unsigned short)x[e2*2+1]) * bf2f((unsigned short)y[e2*2+1]);
    unsigned pk;
    asm volatile("v_cvt_pk_bf16_f32 %0, %1, %2" : "=v"(pk) : "v"(p0), "v"(p1));
    o.u[e2] = pk;
  }
  return o.v;
}
// async global->LDS 16B copy: global src per-lane, LDS dest wave-uniform + lane*16
__device__ __forceinline__ void gload_lds16(const char* g, char* l){
  __builtin_amdgcn_global_load_lds(
      (const __attribute__((address_space(1))) unsigned int*)g,
      (__attribute__((address_space(3))) unsigned int*)l,
      16, 0, 0);
}
// swizzled LDS byte offset for a [rows][768] bf16 panel (coef_gemm staging)
__device__ __forceinline__ int lds_off(int row, int k){
  return row * (H_ * 2) + ((k * 2) ^ ((row & 15) << 4));
}

// ---------------- prep: pack_h + pack_weights + pairs fused ----------------

#define PH_BLKS 3072   // 786432/256
#define PW_BLKS 288    // 73728/256
#define PR_BLKS 33     // ceil(8256/256)

__global__ void prep(const float* __restrict__ h, const float* __restrict__ Wcat,
                     unsigned short* __restrict__ hb,
                     unsigned short* __restrict__ Wsum,
                     unsigned short* __restrict__ Wdif,
                     unsigned short* __restrict__ W4s,
                     int* __restrict__ ii, int* __restrict__ jj){
  const int bid = blockIdx.x;
  if (bid < PH_BLKS){
    int idx = bid * 256 + threadIdx.x;
    hb[idx] = f2bf(h[idx]);
  } else if (bid < PH_BLKS + PW_BLKS){
    int idx = (bid - PH_BLKS) * 256 + threadIdx.x;   // < 96*768
    int o = idx / H_, col = idx % H_;
    bf16x8 vs, vd, v4;
    #pragma unroll
    for (int e = 0; e < 8; e++){
      int hrow = o * 8 + e;
      float w1 = Wcat[hrow * H_ + col];
      float w2 = Wcat[(H_ + hrow) * H_ + col];
      float w3 = Wcat[(2 * H_ + hrow) * H_ + col];
      float w4 = Wcat[(3 * H_ + hrow) * H_ + col];
      vs[e] = (short)f2bf(w1 + w3);
      vd[e] = (short)f2bf(w2 - w3);
      v4[e] = (short)f2bf(w4);
    }
    int pbase = (o * H_ + col) * 8;
    *(bf16x8*)(Wsum + pbase) = vs;
    *(bf16x8*)(Wdif + pbase) = vd;
    *(bf16x8*)(W4s + pbase)  = v4;
  } else {
    int p = (bid - PH_BLKS - PW_BLKS) * 256 + threadIdx.x;
    if (p < P_){
      int i = 0, off = 0;
      while (off + (N_ - i) <= p){ off += (N_ - i); i++; }
      ii[p] = i; jj[p] = i + (p - off);
    }
  }
}

// ---------------- phase 1: Acoef = h@(W1+W3)+bW, Bcoef = h@(W2-W3)  (bf16 out) ----------------

__global__ __launch_bounds__(512, 4) void coef_gemm(
    const unsigned short* __restrict__ hb,
    const unsigned short* __restrict__ Wsum,
    const unsigned short* __restrict__ Wdif,
    const float* __restrict__ bW,
    unsigned short* __restrict__ Acoef, unsigned short* __restrict__ Bcoef){
  const int sel = blockIdx.y;                 // 0 -> Acoef, 1 -> Bcoef
  const unsigned short* Wp = sel ? Wdif : Wsum;
  unsigned short* out = sel ? Bcoef : Acoef;
  const int growb = blockIdx.x * 16;          // 16 rows of the 1024 flat rows

  __shared__ char As[16 * H_ * 2];            // 24 KiB swizzled bf16 panel

  const int tid = threadIdx.x;
  { // stage 16 hb rows, k-interleaved
    int r = tid >> 5;          // 0..15
    int c = tid & 31;          // 0..31
    const unsigned short* src = hb + (growb + r) * H_;
    #pragma unroll
    for (int kk = 0; kk < 3; kk++){
      int k = kk * 256 + c * 8;
      bf16x8 v = *(const bf16x8*)(src + k);
      *(bf16x8*)(As + lds_off(r, k)) = v;
    }
  }
  __syncthreads();

  const int lane = tid & 63;
  const int wn = tid >> 6;      // 0..7 : 96-col group
  const int hi = lane >> 4;     // 0..3
  const int l15 = lane & 15;
  const int colbase = wn * 96 + l15;

  f32x4 acc[6] = {};

  // register double-buffered B prefetch (stride one k-step = 4*H_ frags)
  const bf16x8* wp = (const bf16x8*)Wp + hi * H_ + colbase;
  bf16x8 bc0 = wp[0], bc1 = wp[16], bc2 = wp[32], bc3 = wp[48], bc4 = wp[64], bc5 = wp[80];
  wp += 4 * H_;
  for (int step = 0; step < 24; ++step){
    bf16x8 bn0 = wp[0], bn1 = wp[16], bn2 = wp[32], bn3 = wp[48], bn4 = wp[64], bn5 = wp[80];
    wp += 4 * H_;   // last iter reads past Wp into adjacent ws region: safe, discarded
    bf16x8 a = *(const bf16x8*)(As + lds_off(l15, step * 32 + hi * 8));
    acc[0] = __builtin_amdgcn_mfma_f32_16x16x32_bf16(a, bc0, acc[0], 0, 0, 0);
    acc[1] = __builtin_amdgcn_mfma_f32_16x16x32_bf16(a, bc1, acc[1], 0, 0, 0);
    acc[2] = __builtin_amdgcn_mfma_f32_16x16x32_bf16(a, bc2, acc[2], 0, 0, 0);
    acc[3] = __builtin_amdgcn_mfma_f32_16x16x32_bf16(a, bc3, acc[3], 0, 0, 0);
    acc[4] = __builtin_amdgcn_mfma_f32_16x16x32_bf16(a, bc4, acc[4], 0, 0, 0);
    acc[5] = __builtin_amdgcn_mfma_f32_16x16x32_bf16(a, bc5, acc[5], 0, 0, 0);
    bc0 = bn0; bc1 = bn1; bc2 = bn2; bc3 = bn3; bc4 = bn4; bc5 = bn5;
  }

  #pragma unroll
  for (int ni = 0; ni < 6; ni++){
    int col = colbase + ni * 16;
    float bw = (sel == 0) ? bW[col] : 0.f;
    #pragma unroll
    for (int r = 0; r < 4; r++){
      int grow = growb + hi * 4 + r;
      out[grow * H_ + col] = f2bf(acc[ni][r] + bw);
    }
  }
}

// ---------------- phase 2: fused span GEMM + tanh + online softmax-pool ----------------
// TP=96 pairs/block, 512 threads / 8 waves @ 2 waves/SIMD (256-reg budget).
// Wave = 96 rows x 96 cols: acc[6][6] (144 f32, AGPR-side of unified file).
// B (W4): per-k-step 48KB slab staged block-wide via global_load_lds,
// double-buffered; a full slab is in flight across each step -> L2 BW
// saturation (register prefetch maxed at ~1.5KB in flight -> 40% eff).
// A (products): k=128 slabs, reg-staged 4 steps early. One barrier per step.

__global__ __launch_bounds__(512, 2)
void spans_fused(
    const unsigned short* __restrict__ hb,
    const unsigned short* __restrict__ Acoef,
    const unsigned short* __restrict__ Bcoef,
    const unsigned short* __restrict__ W4s,
    const float* __restrict__ hhat,
    const int* __restrict__ ii,
    const int* __restrict__ jj,
    float* __restrict__ pm, float* __restrict__ pl, float* __restrict__ pacc){
  __shared__ char Bsl[2][BSLAB];       // 2 x 48 KB W4 k-step slices (linear)
  __shared__ char Pp[2][TP * 256];     // 2 x 24 KB product k-slabs (swizzled)
  __shared__ int iis[TP], jjs[TP];
  __shared__ float sbuf[8][TP];
  __shared__ float wbuf[TP];
  __shared__ float Msh;

  const int bid = blockIdx.x;
  const int b = bid / NBLK;
  const int p0 = (bid % NBLK) * TP;
  const int tid = threadIdx.x;

  if (tid < TP){ iis[tid] = ii[p0 + tid]; jjs[tid] = jj[p0 + tid]; }
  __syncthreads();

  const int lane = tid & 63;
  const int wave = tid >> 6;     // 0..7 : 96-col group
  const int hi = lane >> 4;      // 0..3
  const int l15 = lane & 15;
  const int colbase = wave * 96 + l15;
  const char* w4b = (const char*)W4s;
  const int bchunk = wave * 6144;      // this wave's 6KB share of a 48KB slice

  // product staging identity: 3 chunks/thread (96 rows x 16 k-octs per slab)
  int rch[3], cch[3];
  const unsigned short *hpr[3], *hqr[3];
  #pragma unroll
  for (int t = 0; t < 3; t++){
    int cid = tid + t * 512;
    rch[t] = cid >> 4; cch[t] = cid & 15;
    hpr[t] = hb + (b * N_ + iis[rch[t]]) * H_;
    hqr[t] = hb + (b * N_ + jjs[rch[t]]) * H_;
  }

  // ---- prologue ----
  bf16x8 va[3], vb[3];
  #pragma unroll
  for (int t = 0; t < 3; t++){
    va[t] = *(const bf16x8*)(hpr[t] + cch[t] * 8);
    vb[t] = *(const bf16x8*)(hqr[t] + cch[t] * 8);
  }
  // issue B slice 0 (completes at first barrier)
  #pragma unroll
  for (int q = 0; q < 6; q++)
    gload_lds16(w4b + bchunk + q * 1024 + lane * 16, Bsl[0] + bchunk + q * 1024);

  // accumulator init = Acoef[i,col] + Bcoef[j,col] (bf16; MFMA C-in)
  f32x4 acc[6][6];
  #pragma unroll
  for (int mg = 0; mg < 6; mg++){
    #pragma unroll
    for (int r = 0; r < 4; r++){
      int rowl = mg * 16 + hi * 4 + r;
      const unsigned short* ap = Acoef + (b * N_ + iis[rowl]) * H_ + colbase;
      const unsigned short* bp = Bcoef + (b * N_ + jjs[rowl]) * H_ + colbase;
      #pragma unroll
      for (int ni = 0; ni < 6; ni++)
        acc[mg][ni][r] = bf2f(ap[ni * 16]) + bf2f(bp[ni * 16]);
    }
  }
  // write product slab 0
  #pragma unroll
  for (int t = 0; t < 3; t++)
    *(bf16x8*)(Pp[0] + rch[t] * 256 + ((cch[t] * 16) ^ ((rch[t] & 15) << 4))) =
        prodpack(va[t], vb[t]);
  __syncthreads();

  // ---- main loop: 6 product slabs x 4 k-steps; B buffer = ts&1 (4|slab stride)
  char* pcur = Pp[0];
  char* pnxt = Pp[1];
  for (int s = 0; s < 6; ++s){
    if (s < 5){
      const int kg = (s + 1) * 128;
      #pragma unroll
      for (int t = 0; t < 3; t++){
        va[t] = *(const bf16x8*)(hpr[t] + kg + cch[t] * 8);
        vb[t] = *(const bf16x8*)(hqr[t] + kg + cch[t] * 8);
      }
    }
    #pragma unroll
    for (int ts = 0; ts < 4; ++ts){
      // issue next B slice into the other buffer (readers of it finished last step)
      if (ts < 3 || s < 5){
        const char* src = w4b + (s * 4 + ts + 1) * BSLAB + bchunk;
        #pragma unroll
        for (int q = 0; q < 6; q++)
          gload_lds16(src + q * 1024 + lane * 16,
                      Bsl[(ts + 1) & 1] + bchunk + q * 1024);
      }
      // B fragments for this step (conflict-free: 8 words/bank uniform)
      const char* bb = Bsl[ts & 1] + (hi * H_ + colbase) * 16;
      bf16x8 bfr[6];
      #pragma unroll
      for (int ni = 0; ni < 6; ni++)
        bfr[ni] = *(const bf16x8*)(bb + ni * 256);
      const int klb = ts * 64 + hi * 16;
      __builtin_amdgcn_s_setprio(1);
      #pragma unroll
      for (int mg = 0; mg < 6; mg++){
        bf16x8 am = *(const bf16x8*)(pcur + (mg * 16 + l15) * 256 + (klb ^ (l15 << 4)));
        #pragma unroll
        for (int ni = 0; ni < 6; ni++)
          acc[mg][ni] = __builtin_amdgcn_mfma_f32_16x16x32_bf16(am, bfr[ni], acc[mg][ni], 0, 0, 0);
      }
      __builtin_amdgcn_s_setprio(0);
      // write next product slab (read starts after next slab's first barrier)
      if (ts == 3 && s < 5){
        #pragma unroll
        for (int t = 0; t < 3; t++)
          *(bf16x8*)(pnxt + rch[t] * 256 + ((cch[t] * 16) ^ ((rch[t] & 15) << 4))) =
              prodpack(va[t], vb[t]);
      }
      __syncthreads();   // drains vmcnt (B slice t+1) + lgkm (P writes)
    }
    char* tmp = pcur; pcur = pnxt; pnxt = tmp;
  }

  // ---- epilogue: spans = tanh(acc); score partials vs h_hat
  float sc[6][4];
  #pragma unroll
  for (int mg = 0; mg < 6; mg++)
    #pragma unroll
    for (int r = 0; r < 4; r++) sc[mg][r] = 0.f;

  #pragma unroll
  for (int ni = 0; ni < 6; ni++){
    float hh = hhat[colbase + ni * 16];
    #pragma unroll
    for (int mg = 0; mg < 6; mg++){
      #pragma unroll
      for (int r = 0; r < 4; r++){
        float s = tanh_fast(acc[mg][ni][r]);
        acc[mg][ni][r] = s;            // keep span in-register
        sc[mg][r] += s * hh;
      }
    }
  }
  #pragma unroll
  for (int mg = 0; mg < 6; mg++)
    #pragma unroll
    for (int r = 0; r < 4; r++){
      float v = sc[mg][r];
      v += __shfl_xor(v, 1); v += __shfl_xor(v, 2);
      v += __shfl_xor(v, 4); v += __shfl_xor(v, 8);
      sc[mg][r] = v;
    }
  if (l15 == 0){
    #pragma unroll
    for (int mg = 0; mg < 6; mg++)
      #pragma unroll
      for (int r = 0; r < 4; r++)
        sbuf[wave][mg * 16 + hi * 4 + r] = sc[mg][r];
  }
  __syncthreads();

  // per-row total score
  if (tid < TP){
    float s = 0.f;
    #pragma unroll
    for (int w = 0; w < 8; w++) s += sbuf[w][tid];
    wbuf[tid] = s;
  }
  __syncthreads();
  // softmax over 96 rows (wave 0)
  if (tid < 64){
    float a = wbuf[tid];
    float bq = (tid < 32) ? wbuf[64 + tid] : -3.4e38f;
    float m = fmaxf(a, bq);
    #pragma unroll
    for (int off = 1; off < 64; off <<= 1) m = fmaxf(m, __shfl_xor(m, off));
    float l = __expf(a - m) + ((tid < 32) ? __expf(bq - m) : 0.f);
    #pragma unroll
    for (int off = 1; off < 64; off <<= 1) l += __shfl_xor(l, off);
    if (tid == 0){ pm[bid] = m; pl[bid] = l; Msh = m; }
  }
  __syncthreads();
  if (tid < TP) wbuf[tid] = __expf(wbuf[tid] - Msh);
  __syncthreads();

  // weighted span accumulation -> pacc
  #pragma unroll
  for (int ni = 0; ni < 6; ni++){
    float wa = 0.f;
    #pragma unroll
    for (int mg = 0; mg < 6; mg++)
      #pragma unroll
      for (int r = 0; r < 4; r++)
        wa += wbuf[mg * 16 + hi * 4 + r] * acc[mg][ni][r];
    wa += __shfl_xor(wa, 16);
    wa += __shfl_xor(wa, 32);
    if (lane < 16) pacc[bid * H_ + colbase + ni * 16] = wa;
  }
}

// ---------------- phase 3a: column-parallel flash-merge of block partials ----------------

__global__ void merge1(
    const float* __restrict__ pm, const float* __restrict__ pl,
    const float* __restrict__ pacc, float* __restrict__ htg){
  __shared__ float ebuf[NBLK];
  __shared__ float Msh, invLsh;
  __shared__ float part[128];
  const int b = blockIdx.x;
  const int ch = blockIdx.y;
  const int tid = threadIdx.x;   // 256

  if (tid < 64){
    float m = -3.4e38f;
    for (int t = tid; t < NBLK; t += 64) m = fmaxf(m, pm[b * NBLK + t]);
    #pragma unroll
    for (int off = 1; off < 64; off <<= 1) m = fmaxf(m, __shfl_xor(m, off));
    float l = 0.f;
    for (int t = tid; t < NBLK; t += 64) l += pl[b * NBLK + t] * __expf(pm[b * NBLK + t] - m);
    #pragma unroll
    for (int off = 1; off < 64; off <<= 1) l += __shfl_xor(l, off);
    if (tid == 0){ Msh = m; invLsh = 1.f / l; }
  }
  __syncthreads();
  if (tid < NBLK) ebuf[tid] = __expf(pm[b * NBLK + tid] - Msh);
  __syncthreads();
  const int col = ch * 128 + (tid & 127);
  const int half = tid >> 7;
  float a = 0.f;
  for (int t = half; t < NBLK; t += 2) a += pacc[(b * NBLK + t) * H_ + col] * ebuf[t];
  if (half) part[tid & 127] = a;
  __syncthreads();
  if (!half) htg[b * H_ + col] = (a + part[tid]) * invLsh;
}

// ---------------- phase 3b: logits + log_softmax ----------------

__global__ void merge2(
    const float* __restrict__ htg,
    const float* __restrict__ Wout, const float* __restrict__ bout,
    float* __restrict__ outp){
  const int b = blockIdx.x;
  const int lane = threadIdx.x;  // 64
  float a[C_] = {};
  for (int k = lane; k < H_; k += 64){
    float hv = htg[b * H_ + k];
    #pragma unroll
    for (int c = 0; c < C_; c++) a[c] += hv * Wout[k * C_ + c];
  }
  #pragma unroll
  for (int c = 0; c < C_; c++){
    #pragma unroll
    for (int off = 1; off < 64; off <<= 1) a[c] += __shfl_xor(a[c], off);
  }
  if (lane == 0){
    float lg[C_];
    #pragma unroll
    for (int c = 0; c < C_; c++) lg[c] = a[c] + bout[c];
    float mx = lg[0];
    #pragma unroll
    for (int c = 1; c < C_; c++) mx = fmaxf(mx, lg[c]);
    float s = 0.f;
    #pragma unroll
    for (int c = 0; c < C_; c++) s += __expf(lg[c] - mx);
    float ls = __logf(s) + mx;
    #pragma unroll
    for (int c = 0; c < C_; c++) outp[b * C_ + c] = lg[c] - ls;
  }
}

// ---------------- launch ----------------

extern "C" void kernel_launch(void* const* d_in, const int* in_sizes, int n_in,
                              void* d_out, int out_size, void* d_ws, size_t ws_size,
                              hipStream_t stream){
  const float* h    = (const float*)d_in[0];
  const float* Wcat = (const float*)d_in[1];
  const float* bW   = (const float*)d_in[2];
  const float* hhat = (const float*)d_in[3];
  const float* Wout = (const float*)d_in[4];
  const float* bout = (const float*)d_in[5];
  float* outp = (float*)d_out;

  // workspace carve-up (~12 MB total)
  unsigned short* hb   = (unsigned short*)d_ws;        // 786432 bf16
  unsigned short* Wsum = hb + 786432;                  // 589824 bf16 each
  unsigned short* Wdif = Wsum + 589824;
  unsigned short* W4s  = Wdif + 589824;
  unsigned short* Acoef = W4s + 589824;                // 786432 bf16
  unsigned short* Bcoef = Acoef + 786432;              // 786432 bf16
  int* iiA = (int*)(Bcoef + 786432);                   // 8256 i32
  int* jjA = iiA + P_;
  float* pm = (float*)(jjA + P_);                      // 688 f32
  float* pl = pm + (B_ * NBLK);
  float* pacc = pl + (B_ * NBLK);                      // 688*768 f32
  float* htg  = pacc + (B_ * NBLK * H_);               // 8*768 f32

  prep<<<PH_BLKS + PW_BLKS + PR_BLKS, 256, 0, stream>>>(h, Wcat, hb, Wsum, Wdif, W4s, iiA, jjA);
  coef_gemm<<<dim3(64, 2), 512, 0, stream>>>(hb, Wsum, Wdif, bW, Acoef, Bcoef);
  spans_fused<<<B_ * NBLK, 512, 0, stream>>>(hb, Acoef, Bcoef, W4s, hhat, iiA, jjA, pm, pl, pacc);
  merge1<<<dim3(B_, 6), 256, 0, stream>>>(pm, pl, pacc, htg);
  merge2<<<B_, 64, 0, stream>>>(htg, Wout, bout, outp);
}

// Round 10
// 237.438 us; speedup vs baseline: 1.1952x; 1.1952x over previous
//
#include <hip/hip_runtime.h>
#include <hip/hip_bf16.h>

// Fused span-pair + attention-pooling model for MI355X (gfx950).
// B=8, N=128, H=768, C=5, P = N(N+1)/2 = 8256.

#define B_ 8
#define N_ 128
#define H_ 768
#define C_ 5
#define P_ 8256
#define TP 96        // pairs per block (8256 = 86*96 exactly)
#define NBLK 86
#define BSLAB 49152  // one W4 k-step slice: 4 koct * 768 cols * 16 B

typedef short bf16x8 __attribute__((ext_vector_type(8)));
typedef float f32x4 __attribute__((ext_vector_type(4)));

__device__ __forceinline__ float bf2f(unsigned short u){
  union { unsigned u; float f; } v; v.u = ((unsigned)u) << 16; return v.f;
}
__device__ __forceinline__ unsigned short f2bf(float f){
  union { float f; unsigned u; } v; v.f = f;
  unsigned r = v.u + 0x7FFFu + ((v.u >> 16) & 1u);
  return (unsigned short)(r >> 16);
}
__device__ __forceinline__ float tanh_fast(float x){
  float e = __expf(2.f * x);
  return 1.f - 2.f / (e + 1.f);
}
// bf16 product pack via v_cvt_pk_bf16_f32 (RNE, 1 instr per 2 elems)
__device__ __forceinline__ bf16x8 prodpack(bf16x8 x, bf16x8 y){
  union { bf16x8 v; unsigned u[4]; } o;
  #pragma unroll
  for (int e2 = 0; e2 < 4; e2++){
    float p0 = bf2f((unsigned short)x[e2*2])   * bf2f((unsigned short)y[e2*2]);
    float p1 = bf2f((unsigned short)x[e2*2+1]) * bf2f((unsigned short)y[e2*2+1]);
    unsigned pk;
    asm volatile("v_cvt_pk_bf16_f32 %0, %1, %2" : "=v"(pk) : "v"(p0), "v"(p1));
    o.u[e2] = pk;
  }
  return o.v;
}
// async global->LDS 16B copy: global src per-lane, LDS dest wave-uniform + lane*16
__device__ __forceinline__ void gload_lds16(const char* g, char* l){
  __builtin_amdgcn_global_load_lds(
      (const __attribute__((address_space(1))) unsigned int*)g,
      (__attribute__((address_space(3))) unsigned int*)l,
      16, 0, 0);
}
// swizzled LDS byte offset for a [rows][768] bf16 panel (coef_gemm staging)
__device__ __forceinline__ int lds_off(int row, int k){
  return row * (H_ * 2) + ((k * 2) ^ ((row & 15) << 4));
}

// ---------------- prep: pack_h + pack_weights + pairs fused ----------------

#define PH_BLKS 3072   // 786432/256
#define PW_BLKS 288    // 73728/256
#define PR_BLKS 33     // ceil(8256/256)

__global__ void prep(const float* __restrict__ h, const float* __restrict__ Wcat,
                     unsigned short* __restrict__ hb,
                     unsigned short* __restrict__ Wsum,
                     unsigned short* __restrict__ Wdif,
                     unsigned short* __restrict__ W4s,
                     int* __restrict__ ii, int* __restrict__ jj){
  const int bid = blockIdx.x;
  if (bid < PH_BLKS){
    int idx = bid * 256 + threadIdx.x;
    hb[idx] = f2bf(h[idx]);
  } else if (bid < PH_BLKS + PW_BLKS){
    int idx = (bid - PH_BLKS) * 256 + threadIdx.x;   // < 96*768
    int o = idx / H_, col = idx % H_;
    bf16x8 vs, vd, v4;
    #pragma unroll
    for (int e = 0; e < 8; e++){
      int hrow = o * 8 + e;
      float w1 = Wcat[hrow * H_ + col];
      float w2 = Wcat[(H_ + hrow) * H_ + col];
      float w3 = Wcat[(2 * H_ + hrow) * H_ + col];
      float w4 = Wcat[(3 * H_ + hrow) * H_ + col];
      vs[e] = (short)f2bf(w1 + w3);
      vd[e] = (short)f2bf(w2 - w3);
      v4[e] = (short)f2bf(w4);
    }
    int pbase = (o * H_ + col) * 8;
    *(bf16x8*)(Wsum + pbase) = vs;
    *(bf16x8*)(Wdif + pbase) = vd;
    *(bf16x8*)(W4s + pbase)  = v4;
  } else {
    int p = (bid - PH_BLKS - PW_BLKS) * 256 + threadIdx.x;
    if (p < P_){
      int i = 0, off = 0;
      while (off + (N_ - i) <= p){ off += (N_ - i); i++; }
      ii[p] = i; jj[p] = i + (p - off);
    }
  }
}

// ---------------- phase 1: Acoef = h@(W1+W3)+bW, Bcoef = h@(W2-W3)  (bf16 out) ----------------

__global__ __launch_bounds__(512, 4) void coef_gemm(
    const unsigned short* __restrict__ hb,
    const unsigned short* __restrict__ Wsum,
    const unsigned short* __restrict__ Wdif,
    const float* __restrict__ bW,
    unsigned short* __restrict__ Acoef, unsigned short* __restrict__ Bcoef){
  const int sel = blockIdx.y;                 // 0 -> Acoef, 1 -> Bcoef
  const unsigned short* Wp = sel ? Wdif : Wsum;
  unsigned short* out = sel ? Bcoef : Acoef;
  const int growb = blockIdx.x * 16;          // 16 rows of the 1024 flat rows

  __shared__ char As[16 * H_ * 2];            // 24 KiB swizzled bf16 panel

  const int tid = threadIdx.x;
  { // stage 16 hb rows, k-interleaved
    int r = tid >> 5;          // 0..15
    int c = tid & 31;          // 0..31
    const unsigned short* src = hb + (growb + r) * H_;
    #pragma unroll
    for (int kk = 0; kk < 3; kk++){
      int k = kk * 256 + c * 8;
      bf16x8 v = *(const bf16x8*)(src + k);
      *(bf16x8*)(As + lds_off(r, k)) = v;
    }
  }
  __syncthreads();

  const int lane = tid & 63;
  const int wn = tid >> 6;      // 0..7 : 96-col group
  const int hi = lane >> 4;     // 0..3
  const int l15 = lane & 15;
  const int colbase = wn * 96 + l15;

  f32x4 acc[6] = {};

  // register double-buffered B prefetch (stride one k-step = 4*H_ frags)
  const bf16x8* wp = (const bf16x8*)Wp + hi * H_ + colbase;
  bf16x8 bc0 = wp[0], bc1 = wp[16], bc2 = wp[32], bc3 = wp[48], bc4 = wp[64], bc5 = wp[80];
  wp += 4 * H_;
  for (int step = 0; step < 24; ++step){
    bf16x8 bn0 = wp[0], bn1 = wp[16], bn2 = wp[32], bn3 = wp[48], bn4 = wp[64], bn5 = wp[80];
    wp += 4 * H_;   // last iter reads past Wp into adjacent ws region: safe, discarded
    bf16x8 a = *(const bf16x8*)(As + lds_off(l15, step * 32 + hi * 8));
    acc[0] = __builtin_amdgcn_mfma_f32_16x16x32_bf16(a, bc0, acc[0], 0, 0, 0);
    acc[1] = __builtin_amdgcn_mfma_f32_16x16x32_bf16(a, bc1, acc[1], 0, 0, 0);
    acc[2] = __builtin_amdgcn_mfma_f32_16x16x32_bf16(a, bc2, acc[2], 0, 0, 0);
    acc[3] = __builtin_amdgcn_mfma_f32_16x16x32_bf16(a, bc3, acc[3], 0, 0, 0);
    acc[4] = __builtin_amdgcn_mfma_f32_16x16x32_bf16(a, bc4, acc[4], 0, 0, 0);
    acc[5] = __builtin_amdgcn_mfma_f32_16x16x32_bf16(a, bc5, acc[5], 0, 0, 0);
    bc0 = bn0; bc1 = bn1; bc2 = bn2; bc3 = bn3; bc4 = bn4; bc5 = bn5;
  }

  #pragma unroll
  for (int ni = 0; ni < 6; ni++){
    int col = colbase + ni * 16;
    float bw = (sel == 0) ? bW[col] : 0.f;
    #pragma unroll
    for (int r = 0; r < 4; r++){
      int grow = growb + hi * 4 + r;
      out[grow * H_ + col] = f2bf(acc[ni][r] + bw);
    }
  }
}

// ---------------- phase 2: fused span GEMM + tanh + online softmax-pool ----------------
// TP=96 pairs/block, 1024 threads / 16 waves (4/SIMD, 128-VGPR cap).
// Wave = 48 rows x 96 cols: acc[3][6] = 72 f32 (fits; R7/R9's 144 spilled).
// B (W4): per-k-step 48KB slice staged block-wide via global_load_lds,
// double-buffered; full slab in flight per step -> L2 BW saturation.
// A (products): k=128 double-buffered slabs, reg-staged one slab early.
// One barrier per step: vmcnt drain = B-slice + product-write completion.

__global__ __launch_bounds__(1024, 4)
void spans_fused(
    const unsigned short* __restrict__ hb,
    const unsigned short* __restrict__ Acoef,
    const unsigned short* __restrict__ Bcoef,
    const unsigned short* __restrict__ W4s,
    const float* __restrict__ hhat,
    const int* __restrict__ ii,
    const int* __restrict__ jj,
    float* __restrict__ pm, float* __restrict__ pl, float* __restrict__ pacc){
  __shared__ char Bsl[2][BSLAB];       // 2 x 48 KB W4 k-step slices (linear)
  __shared__ char Pp[2][TP * 256];     // 2 x 24 KB product k-slabs (swizzled)
  __shared__ int iis[TP], jjs[TP];
  __shared__ float sbuf[8][TP];
  __shared__ float wbuf[TP];
  __shared__ float obuf[2][H_];
  __shared__ float Msh;

  const int bid = blockIdx.x;
  const int b = bid / NBLK;
  const int p0 = (bid % NBLK) * TP;
  const int tid = threadIdx.x;

  if (tid < TP){ iis[tid] = ii[p0 + tid]; jjs[tid] = jj[p0 + tid]; }
  __syncthreads();

  const int lane = tid & 63;
  const int wave = tid >> 6;     // 0..15
  const int wm = wave >> 3;      // 0..1 : 48-row half
  const int wn = wave & 7;       // 0..7 : 96-col group
  const int hi = lane >> 4;      // 0..3
  const int l15 = lane & 15;
  const int colbase = wn * 96 + l15;
  const int rowbase = wm * 48;
  const char* w4b = (const char*)W4s;
  const int bchunk = wave * 3072;      // this wave's 3KB share of a 48KB slice

  // product staging: chunk0 = tid (rows 0..63), chunk1 = 1024+tid (rows 64..95, tid<512)
  const int r0 = tid >> 4, c0 = tid & 15;
  const int r1 = 64 + (tid >> 4), c1 = tid & 15;    // valid if tid<512
  const unsigned short* hp0 = hb + (b * N_ + iis[r0]) * H_;
  const unsigned short* hq0 = hb + (b * N_ + jjs[r0]) * H_;
  const unsigned short* hp1 = (tid < 512) ? hb + (b * N_ + iis[r1]) * H_ : hp0;
  const unsigned short* hq1 = (tid < 512) ? hb + (b * N_ + jjs[r1]) * H_ : hq0;
  const int po0 = r0 * 256 + ((c0 * 16) ^ ((r0 & 15) << 4));
  const int po1 = r1 * 256 + ((c1 * 16) ^ ((r1 & 15) << 4));

  // ---- prologue ----
  bf16x8 va0 = *(const bf16x8*)(hp0 + c0 * 8);
  bf16x8 vb0 = *(const bf16x8*)(hq0 + c0 * 8);
  bf16x8 va1 = *(const bf16x8*)(hp1 + c1 * 8);
  bf16x8 vb1 = *(const bf16x8*)(hq1 + c1 * 8);
  // issue B slice 0 (completes at first barrier)
  #pragma unroll
  for (int q = 0; q < 3; q++)
    gload_lds16(w4b + bchunk + q * 1024 + lane * 16, Bsl[0] + bchunk + q * 1024);

  // accumulator init = Acoef[i,col] + Bcoef[j,col] (bf16; MFMA C-in)
  f32x4 acc[3][6];
  #pragma unroll
  for (int mg = 0; mg < 3; mg++){
    #pragma unroll
    for (int r = 0; r < 4; r++){
      int rowl = rowbase + mg * 16 + hi * 4 + r;
      const unsigned short* ap = Acoef + (b * N_ + iis[rowl]) * H_ + colbase;
      const unsigned short* bp = Bcoef + (b * N_ + jjs[rowl]) * H_ + colbase;
      #pragma unroll
      for (int ni = 0; ni < 6; ni++)
        acc[mg][ni][r] = bf2f(ap[ni * 16]) + bf2f(bp[ni * 16]);
    }
  }
  // write product slab 0
  *(bf16x8*)(Pp[0] + po0) = prodpack(va0, vb0);
  if (tid < 512) *(bf16x8*)(Pp[0] + po1) = prodpack(va1, vb1);
  __syncthreads();

  // ---- main loop: 6 product slabs x 4 k-steps; B buffer = ts&1 (4|slab stride)
  const char* pcur = Pp[0];
  char* pnxt = Pp[1];
  for (int s = 0; s < 6; ++s){
    if (s < 5){
      const int kg = (s + 1) * 128;
      va0 = *(const bf16x8*)(hp0 + kg + c0 * 8);
      vb0 = *(const bf16x8*)(hq0 + kg + c0 * 8);
      va1 = *(const bf16x8*)(hp1 + kg + c1 * 8);
      vb1 = *(const bf16x8*)(hq1 + kg + c1 * 8);
    }
    #pragma unroll
    for (int ts = 0; ts < 4; ++ts){
      // issue next B slice into the other buffer
      if (ts < 3 || s < 5){
        const char* src = w4b + (s * 4 + ts + 1) * BSLAB + bchunk;
        #pragma unroll
        for (int q = 0; q < 3; q++)
          gload_lds16(src + q * 1024 + lane * 16,
                      Bsl[(ts + 1) & 1] + bchunk + q * 1024);
      }
      const int klb = ts * 64 + hi * 16;
      const char* bb = Bsl[ts & 1] + (hi * H_ + colbase) * 16;
      bf16x8 a0 = *(const bf16x8*)(pcur + (rowbase      + l15) * 256 + (klb ^ (l15 << 4)));
      bf16x8 a1 = *(const bf16x8*)(pcur + (rowbase + 16 + l15) * 256 + (klb ^ (l15 << 4)));
      bf16x8 a2 = *(const bf16x8*)(pcur + (rowbase + 32 + l15) * 256 + (klb ^ (l15 << 4)));
      __builtin_amdgcn_s_setprio(1);
      #pragma unroll
      for (int ni = 0; ni < 6; ni++){
        bf16x8 bfr = *(const bf16x8*)(bb + ni * 256);
        acc[0][ni] = __builtin_amdgcn_mfma_f32_16x16x32_bf16(a0, bfr, acc[0][ni], 0, 0, 0);
        acc[1][ni] = __builtin_amdgcn_mfma_f32_16x16x32_bf16(a1, bfr, acc[1][ni], 0, 0, 0);
        acc[2][ni] = __builtin_amdgcn_mfma_f32_16x16x32_bf16(a2, bfr, acc[2][ni], 0, 0, 0);
      }
      __builtin_amdgcn_s_setprio(0);
      // write next product slab (readers start after the following barrier)
      if (ts == 3 && s < 5){
        *(bf16x8*)(pnxt + po0) = prodpack(va0, vb0);
        if (tid < 512) *(bf16x8*)(pnxt + po1) = prodpack(va1, vb1);
      }
      __syncthreads();   // drains vmcnt (B slice) + lgkm (P writes)
    }
    char* tmp = (char*)pcur; pcur = pnxt; pnxt = tmp;
  }

  // ---- epilogue: spans = tanh(acc); score partials vs h_hat
  float sc[3][4];
  #pragma unroll
  for (int mg = 0; mg < 3; mg++)
    #pragma unroll
    for (int r = 0; r < 4; r++) sc[mg][r] = 0.f;

  #pragma unroll
  for (int ni = 0; ni < 6; ni++){
    float hh = hhat[colbase + ni * 16];
    #pragma unroll
    for (int mg = 0; mg < 3; mg++){
      #pragma unroll
      for (int r = 0; r < 4; r++){
        float s = tanh_fast(acc[mg][ni][r]);
        acc[mg][ni][r] = s;            // keep span in-register
        sc[mg][r] += s * hh;
      }
    }
  }
  #pragma unroll
  for (int mg = 0; mg < 3; mg++)
    #pragma unroll
    for (int r = 0; r < 4; r++){
      float v = sc[mg][r];
      v += __shfl_xor(v, 1); v += __shfl_xor(v, 2);
      v += __shfl_xor(v, 4); v += __shfl_xor(v, 8);
      sc[mg][r] = v;
    }
  if (l15 == 0){
    #pragma unroll
    for (int mg = 0; mg < 3; mg++)
      #pragma unroll
      for (int r = 0; r < 4; r++)
        sbuf[wn][rowbase + mg * 16 + hi * 4 + r] = sc[mg][r];
  }
  __syncthreads();

  // per-row total score (two wm halves wrote disjoint row ranges)
  if (tid < TP){
    float s = 0.f;
    #pragma unroll
    for (int w = 0; w < 8; w++) s += sbuf[w][tid];
    wbuf[tid] = s;
  }
  __syncthreads();
  // softmax over 96 rows (wave 0)
  if (tid < 64){
    float a = wbuf[tid];
    float bq = (tid < 32) ? wbuf[64 + tid] : -3.4e38f;
    float m = fmaxf(a, bq);
    #pragma unroll
    for (int off = 1; off < 64; off <<= 1) m = fmaxf(m, __shfl_xor(m, off));
    float l = __expf(a - m) + ((tid < 32) ? __expf(bq - m) : 0.f);
    #pragma unroll
    for (int off = 1; off < 64; off <<= 1) l += __shfl_xor(l, off);
    if (tid == 0){ pm[bid] = m; pl[bid] = l; Msh = m; }
  }
  __syncthreads();
  if (tid < TP) wbuf[tid] = __expf(wbuf[tid] - Msh);
  __syncthreads();

  // weighted span accumulation: per-wm partials, then combine
  #pragma unroll
  for (int ni = 0; ni < 6; ni++){
    float wa = 0.f;
    #pragma unroll
    for (int mg = 0; mg < 3; mg++)
      #pragma unroll
      for (int r = 0; r < 4; r++)
        wa += wbuf[rowbase + mg * 16 + hi * 4 + r] * acc[mg][ni][r];
    wa += __shfl_xor(wa, 16);
    wa += __shfl_xor(wa, 32);
    if (lane < 16) obuf[wm][colbase + ni * 16] = wa;
  }
  __syncthreads();
  for (int col = tid; col < H_; col += 1024)
    pacc[bid * H_ + col] = obuf[0][col] + obuf[1][col];
}

// ---------------- phase 3a: column-parallel flash-merge of block partials ----------------

__global__ void merge1(
    const float* __restrict__ pm, const float* __restrict__ pl,
    const float* __restrict__ pacc, float* __restrict__ htg){
  __shared__ float ebuf[NBLK];
  __shared__ float Msh, invLsh;
  __shared__ float part[128];
  const int b = blockIdx.x;
  const int ch = blockIdx.y;
  const int tid = threadIdx.x;   // 256

  if (tid < 64){
    float m = -3.4e38f;
    for (int t = tid; t < NBLK; t += 64) m = fmaxf(m, pm[b * NBLK + t]);
    #pragma unroll
    for (int off = 1; off < 64; off <<= 1) m = fmaxf(m, __shfl_xor(m, off));
    float l = 0.f;
    for (int t = tid; t < NBLK; t += 64) l += pl[b * NBLK + t] * __expf(pm[b * NBLK + t] - m);
    #pragma unroll
    for (int off = 1; off < 64; off <<= 1) l += __shfl_xor(l, off);
    if (tid == 0){ Msh = m; invLsh = 1.f / l; }
  }
  __syncthreads();
  if (tid < NBLK) ebuf[tid] = __expf(pm[b * NBLK + tid] - Msh);
  __syncthreads();
  const int col = ch * 128 + (tid & 127);
  const int half = tid >> 7;
  float a = 0.f;
  for (int t = half; t < NBLK; t += 2) a += pacc[(b * NBLK + t) * H_ + col] * ebuf[t];
  if (half) part[tid & 127] = a;
  __syncthreads();
  if (!half) htg[b * H_ + col] = (a + part[tid]) * invLsh;
}

// ---------------- phase 3b: logits + log_softmax ----------------

__global__ void merge2(
    const float* __restrict__ htg,
    const float* __restrict__ Wout, const float* __restrict__ bout,
    float* __restrict__ outp){
  const int b = blockIdx.x;
  const int lane = threadIdx.x;  // 64
  float a[C_] = {};
  for (int k = lane; k < H_; k += 64){
    float hv = htg[b * H_ + k];
    #pragma unroll
    for (int c = 0; c < C_; c++) a[c] += hv * Wout[k * C_ + c];
  }
  #pragma unroll
  for (int c = 0; c < C_; c++){
    #pragma unroll
    for (int off = 1; off < 64; off <<= 1) a[c] += __shfl_xor(a[c], off);
  }
  if (lane == 0){
    float lg[C_];
    #pragma unroll
    for (int c = 0; c < C_; c++) lg[c] = a[c] + bout[c];
    float mx = lg[0];
    #pragma unroll
    for (int c = 1; c < C_; c++) mx = fmaxf(mx, lg[c]);
    float s = 0.f;
    #pragma unroll
    for (int c = 0; c < C_; c++) s += __expf(lg[c] - mx);
    float ls = __logf(s) + mx;
    #pragma unroll
    for (int c = 0; c < C_; c++) outp[b * C_ + c] = lg[c] - ls;
  }
}

// ---------------- launch ----------------

extern "C" void kernel_launch(void* const* d_in, const int* in_sizes, int n_in,
                              void* d_out, int out_size, void* d_ws, size_t ws_size,
                              hipStream_t stream){
  const float* h    = (const float*)d_in[0];
  const float* Wcat = (const float*)d_in[1];
  const float* bW   = (const float*)d_in[2];
  const float* hhat = (const float*)d_in[3];
  const float* Wout = (const float*)d_in[4];
  const float* bout = (const float*)d_in[5];
  float* outp = (float*)d_out;

  // workspace carve-up (~12 MB total)
  unsigned short* hb   = (unsigned short*)d_ws;        // 786432 bf16
  unsigned short* Wsum = hb + 786432;                  // 589824 bf16 each
  unsigned short* Wdif = Wsum + 589824;
  unsigned short* W4s  = Wdif + 589824;
  unsigned short* Acoef = W4s + 589824;                // 786432 bf16
  unsigned short* Bcoef = Acoef + 786432;              // 786432 bf16
  int* iiA = (int*)(Bcoef + 786432);                   // 8256 i32
  int* jjA = iiA + P_;
  float* pm = (float*)(jjA + P_);                      // 688 f32
  float* pl = pm + (B_ * NBLK);
  float* pacc = pl + (B_ * NBLK);                      // 688*768 f32
  float* htg  = pacc + (B_ * NBLK * H_);               // 8*768 f32

  prep<<<PH_BLKS + PW_BLKS + PR_BLKS, 256, 0, stream>>>(h, Wcat, hb, Wsum, Wdif, W4s, iiA, jjA);
  coef_gemm<<<dim3(64, 2), 512, 0, stream>>>(hb, Wsum, Wdif, bW, Acoef, Bcoef);
  spans_fused<<<B_ * NBLK, 1024, 0, stream>>>(hb, Acoef, Bcoef, W4s, hhat, iiA, jjA, pm, pl, pacc);
  merge1<<<dim3(B_, 6), 256, 0, stream>>>(pm, pl, pacc, htg);
  merge2<<<B_, 64, 0, stream>>>(htg, Wout, bout, outp);
}

// Round 11
// 203.944 us; speedup vs baseline: 1.3915x; 1.1642x over previous
//
#include <hip/hip_runtime.h>
#include <hip/hip_bf16.h>

// Fused span-pair + attention-pooling model for MI355X (gfx950).
// B=8, N=128, H=768, C=5, P = N(N+1)/2 = 8256.

#define B_ 8
#define N_ 128
#define H_ 768
#define C_ 5
#define P_ 8256
#define TP 64
#define NBLK 129     // P_/TP
#define BSLAB 49152  // one W4 k-step slice: 4 koct * 768 cols * 16 B

typedef short bf16x8 __attribute__((ext_vector_type(8)));
typedef float f32x4 __attribute__((ext_vector_type(4)));

__device__ __forceinline__ float bf2f(unsigned short u){
  union { unsigned u; float f; } v; v.u = ((unsigned)u) << 16; return v.f;
}
__device__ __forceinline__ unsigned short f2bf(float f){
  union { float f; unsigned u; } v; v.f = f;
  unsigned r = v.u + 0x7FFFu + ((v.u >> 16) & 1u);
  return (unsigned short)(r >> 16);
}
__device__ __forceinline__ float tanh_fast(float x){
  float e = __expf(2.f * x);
  return 1.f - 2.f / (e + 1.f);
}
// bf16 product pack via v_cvt_pk_bf16_f32 (RNE, 1 instr per 2 elems)
__device__ __forceinline__ bf16x8 prodpack(bf16x8 x, bf16x8 y){
  union { bf16x8 v; unsigned u[4]; } o;
  #pragma unroll
  for (int e2 = 0; e2 < 4; e2++){
    float p0 = bf2f((unsigned short)x[e2*2])   * bf2f((unsigned short)y[e2*2]);
    float p1 = bf2f((unsigned short)x[e2*2+1]) * bf2f((unsigned short)y[e2*2+1]);
    unsigned pk;
    asm volatile("v_cvt_pk_bf16_f32 %0, %1, %2" : "=v"(pk) : "v"(p0), "v"(p1));
    o.u[e2] = pk;
  }
  return o.v;
}
// async global->LDS 16B copy: global src per-lane, LDS dest wave-uniform + lane*16
__device__ __forceinline__ void gload_lds16(const char* g, char* l){
  __builtin_amdgcn_global_load_lds(
      (const __attribute__((address_space(1))) unsigned int*)g,
      (__attribute__((address_space(3))) unsigned int*)l,
      16, 0, 0);
}
// swizzled LDS byte offset for a [rows][768] bf16 panel (coef_gemm staging)
__device__ __forceinline__ int lds_off(int row, int k){
  return row * (H_ * 2) + ((k * 2) ^ ((row & 15) << 4));
}

// ---------------- prep: pack_h + pack_weights + pairs fused ----------------

#define PH_BLKS 3072   // 786432/256
#define PW_BLKS 288    // 73728/256
#define PR_BLKS 33     // ceil(8256/256)

__global__ void prep(const float* __restrict__ h, const float* __restrict__ Wcat,
                     unsigned short* __restrict__ hb,
                     unsigned short* __restrict__ Wsum,
                     unsigned short* __restrict__ Wdif,
                     unsigned short* __restrict__ W4s,
                     int* __restrict__ ii, int* __restrict__ jj){
  const int bid = blockIdx.x;
  if (bid < PH_BLKS){
    int idx = bid * 256 + threadIdx.x;
    hb[idx] = f2bf(h[idx]);
  } else if (bid < PH_BLKS + PW_BLKS){
    int idx = (bid - PH_BLKS) * 256 + threadIdx.x;   // < 96*768
    int o = idx / H_, col = idx % H_;
    bf16x8 vs, vd, v4;
    #pragma unroll
    for (int e = 0; e < 8; e++){
      int hrow = o * 8 + e;
      float w1 = Wcat[hrow * H_ + col];
      float w2 = Wcat[(H_ + hrow) * H_ + col];
      float w3 = Wcat[(2 * H_ + hrow) * H_ + col];
      float w4 = Wcat[(3 * H_ + hrow) * H_ + col];
      vs[e] = (short)f2bf(w1 + w3);
      vd[e] = (short)f2bf(w2 - w3);
      v4[e] = (short)f2bf(w4);
    }
    int pbase = (o * H_ + col) * 8;
    *(bf16x8*)(Wsum + pbase) = vs;
    *(bf16x8*)(Wdif + pbase) = vd;
    *(bf16x8*)(W4s + pbase)  = v4;
  } else {
    int p = (bid - PH_BLKS - PW_BLKS) * 256 + threadIdx.x;
    if (p < P_){
      int i = 0, off = 0;
      while (off + (N_ - i) <= p){ off += (N_ - i); i++; }
      ii[p] = i; jj[p] = i + (p - off);
    }
  }
}

// ---------------- phase 1: Acoef = h@(W1+W3)+bW, Bcoef = h@(W2-W3)  (bf16 out) ----------------

__global__ __launch_bounds__(512, 4) void coef_gemm(
    const unsigned short* __restrict__ hb,
    const unsigned short* __restrict__ Wsum,
    const unsigned short* __restrict__ Wdif,
    const float* __restrict__ bW,
    unsigned short* __restrict__ Acoef, unsigned short* __restrict__ Bcoef){
  const int sel = blockIdx.y;                 // 0 -> Acoef, 1 -> Bcoef
  const unsigned short* Wp = sel ? Wdif : Wsum;
  unsigned short* out = sel ? Bcoef : Acoef;
  const int growb = blockIdx.x * 16;          // 16 rows of the 1024 flat rows

  __shared__ char As[16 * H_ * 2];            // 24 KiB swizzled bf16 panel

  const int tid = threadIdx.x;
  { // stage 16 hb rows, k-interleaved
    int r = tid >> 5;          // 0..15
    int c = tid & 31;          // 0..31
    const unsigned short* src = hb + (growb + r) * H_;
    #pragma unroll
    for (int kk = 0; kk < 3; kk++){
      int k = kk * 256 + c * 8;
      bf16x8 v = *(const bf16x8*)(src + k);
      *(bf16x8*)(As + lds_off(r, k)) = v;
    }
  }
  __syncthreads();

  const int lane = tid & 63;
  const int wn = tid >> 6;      // 0..7 : 96-col group
  const int hi = lane >> 4;     // 0..3
  const int l15 = lane & 15;
  const int colbase = wn * 96 + l15;

  f32x4 acc[6] = {};

  // register double-buffered B prefetch (stride one k-step = 4*H_ frags)
  const bf16x8* wp = (const bf16x8*)Wp + hi * H_ + colbase;
  bf16x8 bc0 = wp[0], bc1 = wp[16], bc2 = wp[32], bc3 = wp[48], bc4 = wp[64], bc5 = wp[80];
  wp += 4 * H_;
  for (int step = 0; step < 24; ++step){
    bf16x8 bn0 = wp[0], bn1 = wp[16], bn2 = wp[32], bn3 = wp[48], bn4 = wp[64], bn5 = wp[80];
    wp += 4 * H_;   // last iter reads past Wp into adjacent ws region: safe, discarded
    bf16x8 a = *(const bf16x8*)(As + lds_off(l15, step * 32 + hi * 8));
    acc[0] = __builtin_amdgcn_mfma_f32_16x16x32_bf16(a, bc0, acc[0], 0, 0, 0);
    acc[1] = __builtin_amdgcn_mfma_f32_16x16x32_bf16(a, bc1, acc[1], 0, 0, 0);
    acc[2] = __builtin_amdgcn_mfma_f32_16x16x32_bf16(a, bc2, acc[2], 0, 0, 0);
    acc[3] = __builtin_amdgcn_mfma_f32_16x16x32_bf16(a, bc3, acc[3], 0, 0, 0);
    acc[4] = __builtin_amdgcn_mfma_f32_16x16x32_bf16(a, bc4, acc[4], 0, 0, 0);
    acc[5] = __builtin_amdgcn_mfma_f32_16x16x32_bf16(a, bc5, acc[5], 0, 0, 0);
    bc0 = bn0; bc1 = bn1; bc2 = bn2; bc3 = bn3; bc4 = bn4; bc5 = bn5;
  }

  #pragma unroll
  for (int ni = 0; ni < 6; ni++){
    int col = colbase + ni * 16;
    float bw = (sel == 0) ? bW[col] : 0.f;
    #pragma unroll
    for (int r = 0; r < 4; r++){
      int grow = growb + hi * 4 + r;
      out[grow * H_ + col] = f2bf(acc[ni][r] + bw);
    }
  }
}

// ---------------- phase 2: fused span GEMM + tanh + online softmax-pool ----------------
// TP=64 pairs/block, 1024 threads / 16 waves (4/SIMD).
// Wave = 64 rows x 48 cols: acc[4][3] = 48 f32/lane -- fits the ~64-AGPR
// half of the unified file (R8 compiled clean at this shape; 72+ spills).
// B (W4): per-k-step 48KB slice staged block-wide via global_load_lds,
// double-buffered; a full slice is in flight each step -> covers L2 latency
// (register prefetch maxes ~1.5KB in flight -> the R8 25% MfmaUtil wall).
// A (products): k=128 double-buffered slabs, reg-staged one slab early,
// exactly 1 chunk per thread. One barrier per step (vmcnt drain = completion).

__global__ __launch_bounds__(1024, 4)
void spans_fused(
    const unsigned short* __restrict__ hb,
    const unsigned short* __restrict__ Acoef,
    const unsigned short* __restrict__ Bcoef,
    const unsigned short* __restrict__ W4s,
    const float* __restrict__ hhat,
    const int* __restrict__ ii,
    const int* __restrict__ jj,
    float* __restrict__ pm, float* __restrict__ pl, float* __restrict__ pacc){
  __shared__ char Bsl[2][BSLAB];       // 2 x 48 KB W4 k-step slices (linear)
  __shared__ char Pp[2][TP * 256];     // 2 x 16 KB product k-slabs (swizzled)
  __shared__ int iis[TP], jjs[TP];
  __shared__ float sbuf[16][TP];
  __shared__ float wbuf[TP];

  const int bid = blockIdx.x;
  const int b = bid / NBLK;
  const int p0 = (bid % NBLK) * TP;
  const int tid = threadIdx.x;

  if (tid < TP){ iis[tid] = ii[p0 + tid]; jjs[tid] = jj[p0 + tid]; }
  __syncthreads();

  const int lane = tid & 63;
  const int wave = tid >> 6;     // 0..15 : 48-col group
  const int hi = lane >> 4;      // 0..3
  const int l15 = lane & 15;
  const int colbase = wave * 48 + l15;
  const char* w4b = (const char*)W4s;
  const int bchunk = wave * 3072;      // this wave's 3KB share of a 48KB slice

  // product staging: exactly one chunk per thread (64 rows x 16 k-octs)
  const int r0 = tid >> 4, c0 = tid & 15;
  const unsigned short* hp0 = hb + (b * N_ + iis[r0]) * H_;
  const unsigned short* hq0 = hb + (b * N_ + jjs[r0]) * H_;
  const int po0 = r0 * 256 + ((c0 * 16) ^ ((r0 & 15) << 4));

  // ---- prologue ----
  bf16x8 va0 = *(const bf16x8*)(hp0 + c0 * 8);
  bf16x8 vb0 = *(const bf16x8*)(hq0 + c0 * 8);
  // issue B slice 0 (completes at first barrier)
  #pragma unroll
  for (int q = 0; q < 3; q++)
    gload_lds16(w4b + bchunk + q * 1024 + lane * 16, Bsl[0] + bchunk + q * 1024);

  // accumulator init = Acoef[i,col] + Bcoef[j,col] (bf16; MFMA C-in)
  f32x4 acc[4][3];
  #pragma unroll
  for (int mg = 0; mg < 4; mg++){
    #pragma unroll
    for (int r = 0; r < 4; r++){
      int rowl = mg * 16 + hi * 4 + r;
      const unsigned short* ap = Acoef + (b * N_ + iis[rowl]) * H_ + colbase;
      const unsigned short* bp = Bcoef + (b * N_ + jjs[rowl]) * H_ + colbase;
      #pragma unroll
      for (int ni = 0; ni < 3; ni++)
        acc[mg][ni][r] = bf2f(ap[ni * 16]) + bf2f(bp[ni * 16]);
    }
  }
  // write product slab 0
  *(bf16x8*)(Pp[0] + po0) = prodpack(va0, vb0);
  __syncthreads();

  // ---- main loop: 6 product slabs x 4 k-steps; B buffer parity = step&1
  const char* pcur = Pp[0];
  char* pnxt = Pp[1];
  for (int s = 0; s < 6; ++s){
    if (s < 5){
      const int kg = (s + 1) * 128;
      va0 = *(const bf16x8*)(hp0 + kg + c0 * 8);
      vb0 = *(const bf16x8*)(hq0 + kg + c0 * 8);
    }
    #pragma unroll
    for (int ts = 0; ts < 4; ++ts){
      // issue next B slice into the other buffer
      if (ts < 3 || s < 5){
        const char* src = w4b + (s * 4 + ts + 1) * BSLAB + bchunk;
        #pragma unroll
        for (int q = 0; q < 3; q++)
          gload_lds16(src + q * 1024 + lane * 16,
                      Bsl[(ts + 1) & 1] + bchunk + q * 1024);
      }
      const int klb = ts * 64 + hi * 16;
      const char* bb = Bsl[ts & 1] + (hi * H_ + colbase) * 16;
      bf16x8 bfr0 = *(const bf16x8*)(bb);
      bf16x8 bfr1 = *(const bf16x8*)(bb + 256);
      bf16x8 bfr2 = *(const bf16x8*)(bb + 512);
      bf16x8 a0 = *(const bf16x8*)(pcur + (     l15) * 256 + (klb ^ (l15 << 4)));
      bf16x8 a1 = *(const bf16x8*)(pcur + (16 + l15) * 256 + (klb ^ (l15 << 4)));
      bf16x8 a2 = *(const bf16x8*)(pcur + (32 + l15) * 256 + (klb ^ (l15 << 4)));
      bf16x8 a3 = *(const bf16x8*)(pcur + (48 + l15) * 256 + (klb ^ (l15 << 4)));
      __builtin_amdgcn_s_setprio(1);
      acc[0][0] = __builtin_amdgcn_mfma_f32_16x16x32_bf16(a0, bfr0, acc[0][0], 0, 0, 0);
      acc[1][0] = __builtin_amdgcn_mfma_f32_16x16x32_bf16(a1, bfr0, acc[1][0], 0, 0, 0);
      acc[2][0] = __builtin_amdgcn_mfma_f32_16x16x32_bf16(a2, bfr0, acc[2][0], 0, 0, 0);
      acc[3][0] = __builtin_amdgcn_mfma_f32_16x16x32_bf16(a3, bfr0, acc[3][0], 0, 0, 0);
      acc[0][1] = __builtin_amdgcn_mfma_f32_16x16x32_bf16(a0, bfr1, acc[0][1], 0, 0, 0);
      acc[1][1] = __builtin_amdgcn_mfma_f32_16x16x32_bf16(a1, bfr1, acc[1][1], 0, 0, 0);
      acc[2][1] = __builtin_amdgcn_mfma_f32_16x16x32_bf16(a2, bfr1, acc[2][1], 0, 0, 0);
      acc[3][1] = __builtin_amdgcn_mfma_f32_16x16x32_bf16(a3, bfr1, acc[3][1], 0, 0, 0);
      acc[0][2] = __builtin_amdgcn_mfma_f32_16x16x32_bf16(a0, bfr2, acc[0][2], 0, 0, 0);
      acc[1][2] = __builtin_amdgcn_mfma_f32_16x16x32_bf16(a1, bfr2, acc[1][2], 0, 0, 0);
      acc[2][2] = __builtin_amdgcn_mfma_f32_16x16x32_bf16(a2, bfr2, acc[2][2], 0, 0, 0);
      acc[3][2] = __builtin_amdgcn_mfma_f32_16x16x32_bf16(a3, bfr2, acc[3][2], 0, 0, 0);
      __builtin_amdgcn_s_setprio(0);
      // write next product slab (readers start after the following barrier)
      if (ts == 3 && s < 5)
        *(bf16x8*)(pnxt + po0) = prodpack(va0, vb0);
      __syncthreads();   // drains vmcnt (B slice) + lgkm (P writes)
    }
    char* tmp = (char*)pcur; pcur = pnxt; pnxt = tmp;
  }

  // ---- epilogue: spans = tanh(acc); score partials vs h_hat
  float sc[4][4];
  #pragma unroll
  for (int mg = 0; mg < 4; mg++)
    #pragma unroll
    for (int r = 0; r < 4; r++) sc[mg][r] = 0.f;

  #pragma unroll
  for (int ni = 0; ni < 3; ni++){
    float hh = hhat[colbase + ni * 16];
    #pragma unroll
    for (int mg = 0; mg < 4; mg++){
      #pragma unroll
      for (int r = 0; r < 4; r++){
        float s = tanh_fast(acc[mg][ni][r]);
        acc[mg][ni][r] = s;            // keep span in-register
        sc[mg][r] += s * hh;
      }
    }
  }
  #pragma unroll
  for (int mg = 0; mg < 4; mg++)
    #pragma unroll
    for (int r = 0; r < 4; r++){
      float v = sc[mg][r];
      v += __shfl_xor(v, 1); v += __shfl_xor(v, 2);
      v += __shfl_xor(v, 4); v += __shfl_xor(v, 8);
      sc[mg][r] = v;
    }
  if (l15 == 0){
    #pragma unroll
    for (int mg = 0; mg < 4; mg++)
      #pragma unroll
      for (int r = 0; r < 4; r++)
        sbuf[wave][mg * 16 + hi * 4 + r] = sc[mg][r];
  }
  __syncthreads();

  // block-local softmax weights (wave 0)
  if (tid < TP){
    float s = 0.f;
    #pragma unroll
    for (int w = 0; w < 16; w++) s += sbuf[w][tid];
    float m = s;
    #pragma unroll
    for (int off = 1; off < 64; off <<= 1) m = fmaxf(m, __shfl_xor(m, off));
    float w = __expf(s - m);
    float l = w;
    #pragma unroll
    for (int off = 1; off < 64; off <<= 1) l += __shfl_xor(l, off);
    wbuf[tid] = w;
    if (tid == 0){ pm[bid] = m; pl[bid] = l; }
  }
  __syncthreads();

  // weighted span accumulation -> pacc directly
  #pragma unroll
  for (int ni = 0; ni < 3; ni++){
    float wa = 0.f;
    #pragma unroll
    for (int mg = 0; mg < 4; mg++)
      #pragma unroll
      for (int r = 0; r < 4; r++){
        int rowl = mg * 16 + hi * 4 + r;
        wa += wbuf[rowl] * acc[mg][ni][r];
      }
    wa += __shfl_xor(wa, 16);
    wa += __shfl_xor(wa, 32);
    if (lane < 16) pacc[bid * H_ + colbase + ni * 16] = wa;
  }
}

// ---------------- phase 3a: column-parallel flash-merge of block partials ----------------

__global__ void merge1(
    const float* __restrict__ pm, const float* __restrict__ pl,
    const float* __restrict__ pacc, float* __restrict__ htg){
  __shared__ float ebuf[NBLK];
  __shared__ float Msh, invLsh;
  __shared__ float part[128];
  const int b = blockIdx.x;
  const int ch = blockIdx.y;
  const int tid = threadIdx.x;   // 256

  if (tid < 64){
    float m = -3.4e38f;
    for (int t = tid; t < NBLK; t += 64) m = fmaxf(m, pm[b * NBLK + t]);
    #pragma unroll
    for (int off = 1; off < 64; off <<= 1) m = fmaxf(m, __shfl_xor(m, off));
    float l = 0.f;
    for (int t = tid; t < NBLK; t += 64) l += pl[b * NBLK + t] * __expf(pm[b * NBLK + t] - m);
    #pragma unroll
    for (int off = 1; off < 64; off <<= 1) l += __shfl_xor(l, off);
    if (tid == 0){ Msh = m; invLsh = 1.f / l; }
  }
  __syncthreads();
  if (tid < NBLK) ebuf[tid] = __expf(pm[b * NBLK + tid] - Msh);
  __syncthreads();
  const int col = ch * 128 + (tid & 127);
  const int half = tid >> 7;
  float a = 0.f;
  for (int t = half; t < NBLK; t += 2) a += pacc[(b * NBLK + t) * H_ + col] * ebuf[t];
  if (half) part[tid & 127] = a;
  __syncthreads();
  if (!half) htg[b * H_ + col] = (a + part[tid]) * invLsh;
}

// ---------------- phase 3b: logits + log_softmax ----------------

__global__ void merge2(
    const float* __restrict__ htg,
    const float* __restrict__ Wout, const float* __restrict__ bout,
    float* __restrict__ outp){
  const int b = blockIdx.x;
  const int lane = threadIdx.x;  // 64
  float a[C_] = {};
  for (int k = lane; k < H_; k += 64){
    float hv = htg[b * H_ + k];
    #pragma unroll
    for (int c = 0; c < C_; c++) a[c] += hv * Wout[k * C_ + c];
  }
  #pragma unroll
  for (int c = 0; c < C_; c++){
    #pragma unroll
    for (int off = 1; off < 64; off <<= 1) a[c] += __shfl_xor(a[c], off);
  }
  if (lane == 0){
    float lg[C_];
    #pragma unroll
    for (int c = 0; c < C_; c++) lg[c] = a[c] + bout[c];
    float mx = lg[0];
    #pragma unroll
    for (int c = 1; c < C_; c++) mx = fmaxf(mx, lg[c]);
    float s = 0.f;
    #pragma unroll
    for (int c = 0; c < C_; c++) s += __expf(lg[c] - mx);
    float ls = __logf(s) + mx;
    #pragma unroll
    for (int c = 0; c < C_; c++) outp[b * C_ + c] = lg[c] - ls;
  }
}

// ---------------- launch ----------------

extern "C" void kernel_launch(void* const* d_in, const int* in_sizes, int n_in,
                              void* d_out, int out_size, void* d_ws, size_t ws_size,
                              hipStream_t stream){
  const float* h    = (const float*)d_in[0];
  const float* Wcat = (const float*)d_in[1];
  const float* bW   = (const float*)d_in[2];
  const float* hhat = (const float*)d_in[3];
  const float* Wout = (const float*)d_in[4];
  const float* bout = (const float*)d_in[5];
  float* outp = (float*)d_out;

  // workspace carve-up (~12 MB total)
  unsigned short* hb   = (unsigned short*)d_ws;        // 786432 bf16
  unsigned short* Wsum = hb + 786432;                  // 589824 bf16 each
  unsigned short* Wdif = Wsum + 589824;
  unsigned short* W4s  = Wdif + 589824;
  unsigned short* Acoef = W4s + 589824;                // 786432 bf16
  unsigned short* Bcoef = Acoef + 786432;              // 786432 bf16
  int* iiA = (int*)(Bcoef + 786432);                   // 8256 i32
  int* jjA = iiA + P_;
  float* pm = (float*)(jjA + P_);                      // 1032 f32
  float* pl = pm + (B_ * NBLK);
  float* pacc = pl + (B_ * NBLK);                      // 1032*768 f32
  float* htg  = pacc + (B_ * NBLK * H_);               // 8*768 f32

  prep<<<PH_BLKS + PW_BLKS + PR_BLKS, 256, 0, stream>>>(h, Wcat, hb, Wsum, Wdif, W4s, iiA, jjA);
  coef_gemm<<<dim3(64, 2), 512, 0, stream>>>(hb, Wsum, Wdif, bW, Acoef, Bcoef);
  spans_fused<<<B_ * NBLK, 1024, 0, stream>>>(hb, Acoef, Bcoef, W4s, hhat, iiA, jjA, pm, pl, pacc);
  merge1<<<dim3(B_, 6), 256, 0, stream>>>(pm, pl, pacc, htg);
  merge2<<<B_, 64, 0, stream>>>(htg, Wout, bout, outp);
}